// Round 1
// baseline (7126.247 us; speedup 1.0000x reference)
//
#include <hip/hip_runtime.h>

typedef _Float16 f16;
typedef _Float16 f16x8 __attribute__((ext_vector_type(8)));
typedef float    f32x4 __attribute__((ext_vector_type(4)));

#define SEQ   2048
#define BATCH 64
#define EMBED 256
#define HID   256
#define NC    1024            // 4 gates * HID
#define ROWS  (SEQ*BATCH)     // 131072

// ---------------------------------------------------------------------------
// prep_w: build f16 weight layouts in workspace.
//  Wx_t [1024 col][256 k]  : transposed input-proj weights (col-major rows)
//  Wh_t [1024 col][256 k]  : transposed recurrent weights (for B-frag reg load)
//  Wfrag[2 kfi][64 nt][64 lane][8] : frag-packed W_h for k in [192,256) (LDS slice)
// ---------------------------------------------------------------------------
__global__ __launch_bounds__(256) void prep_w(
    const float* __restrict__ Wix, const float* __restrict__ Wih,
    const float* __restrict__ Wfx, const float* __restrict__ Wfh,
    const float* __restrict__ Wgx, const float* __restrict__ Wgh,
    const float* __restrict__ Wox, const float* __restrict__ Woh,
    f16* __restrict__ Wx_t, f16* __restrict__ Wh_t, f16* __restrict__ Wfrag)
{
  int tid = blockIdx.x*256 + threadIdx.x;
  const float* WX[4] = {Wix, Wfx, Wgx, Wox};
  const float* WH[4] = {Wih, Wfh, Wgh, Woh};
  if (tid < 65536) {
    int which = tid >> 15;          // 0 -> Wx_t, 1 -> Wh_t
    int j  = (tid >> 5) & 1023;     // output column (gate*256 + unit)
    int ko = tid & 31;              // k-octet
    const float* src = (which ? WH : WX)[j >> 8];
    int u = j & 255;
    f16x8 v;
    #pragma unroll
    for (int q = 0; q < 8; ++q) v[q] = (f16)src[(ko*8+q)*HID + u];
    *(f16x8*)((which ? Wh_t : Wx_t) + (size_t)j*256 + ko*8) = v;
  } else if (tid < 65536 + 8192) {
    int r   = tid - 65536;
    int l   = r & 63, gt = (r >> 6) & 63, kfi = r >> 12;
    int col = gt*16 + (l & 15);
    int kbase = 192 + kfi*32 + (l >> 4)*8;
    const float* src = WH[col >> 8];
    int u = col & 255;
    f16x8 v;
    #pragma unroll
    for (int q = 0; q < 8; ++q) v[q] = (f16)src[(kbase+q)*HID + u];
    *(f16x8*)(Wfrag + (size_t)r*8) = v;
  }
}

// ---------------------------------------------------------------------------
// gemm_x: Xp[row][col] = embeds[row][:] @ Wx[:, col] + bias[col], f16 output.
// 64x64 C tile per 256-thread WG; f16 LDS staging with (row&7)<<4 XOR swizzle.
// MFMA layouts (gfx950 16x16x32): A: row=l&15, k=(l>>4)*8+j ; B: col=l&15,
// k=(l>>4)*8+j ; D: col=l&15, row=(l>>4)*4+reg.
// ---------------------------------------------------------------------------
__global__ __launch_bounds__(256) void gemm_x(
    const float* __restrict__ emb, const f16* __restrict__ Bt,
    const float* __restrict__ b0, const float* __restrict__ b1,
    const float* __restrict__ b2, const float* __restrict__ b3,
    f16* __restrict__ Xo)
{
  __shared__ f16 Al[64*256];   // 32 KB
  __shared__ f16 Bl[64*256];   // 32 KB
  int wg = blockIdx.x;
  int R0 = (wg >> 4) * 64;     // row block (one timestep: rows = t*64 + b)
  int C0 = (wg & 15) * 64;     // col block
  int tid = threadIdx.x;

  #pragma unroll
  for (int j = 0; j < 8; ++j) {
    int c = tid + j*256; int row = c >> 5, ci = c & 31;
    const float* ap = emb + (size_t)(R0+row)*EMBED + ci*8;
    f32x4 a0 = *(const f32x4*)ap;
    f32x4 a1 = *(const f32x4*)(ap + 4);
    f16x8 v;
    #pragma unroll
    for (int q = 0; q < 4; ++q) { v[q] = (f16)a0[q]; v[q+4] = (f16)a1[q]; }
    *(f16x8*)((char*)Al + row*512 + ((ci*16) ^ ((row&7)<<4))) = v;
    f16x8 vb = *(const f16x8*)(Bt + (size_t)(C0+row)*256 + ci*8);
    *(f16x8*)((char*)Bl + row*512 + ((ci*16) ^ ((row&7)<<4))) = vb;
  }
  __syncthreads();

  int w = tid >> 6, l = tid & 63, lr = l & 15, lg = l >> 4;
  const float* bp = (C0 < 256) ? b0 : (C0 < 512) ? b1 : (C0 < 768) ? b2 : b3;
  int ub = (C0 & 255) + lr;
  f32x4 cf[4];
  #pragma unroll
  for (int nt = 0; nt < 4; ++nt) { float bv = bp[ub + nt*16]; cf[nt] = (f32x4){bv,bv,bv,bv}; }

  #pragma unroll
  for (int kf = 0; kf < 8; ++kf) {
    int arow = w*16 + lr;
    f16x8 af = *(const f16x8*)((char*)Al + arow*512 + ((kf*64 + lg*16) ^ ((arow&7)<<4)));
    #pragma unroll
    for (int nt = 0; nt < 4; ++nt) {
      int brow = nt*16 + lr;
      f16x8 bf = *(const f16x8*)((char*)Bl + brow*512 + ((kf*64 + lg*16) ^ ((brow&7)<<4)));
      cf[nt] = __builtin_amdgcn_mfma_f32_16x16x32_f16(af, bf, cf[nt], 0, 0, 0);
    }
  }
  #pragma unroll
  for (int nt = 0; nt < 4; ++nt)
    #pragma unroll
    for (int r = 0; r < 4; ++r) {
      int row = R0 + w*16 + lg*4 + r;
      int col = C0 + nt*16 + lr;
      Xo[(size_t)row*NC + col] = (f16)cf[nt][r];
    }
}

// ---------------------------------------------------------------------------
// lstm_rec: one WG per batch element; 512 threads (8 waves). Per step:
// y[1024] = x_t + h @ Wh via MFMA 16x16x32_f16 with h replicated into all 16
// A rows (all C rows/lanes then hold y). Wave w owns global n-tiles w*8..w*8+7
// (gate = w>>1). Wh k<192 lives in per-lane B-fragment registers (WB, 192
// VGPR); k in [192,256) streamed from a frag-packed 128 KB LDS copy.
// h double-buffered in LDS as f16; c kept in VGPR of threads 0..255.
// x_t double-buffered through LDS (prefetch t+1 during step t).
// ---------------------------------------------------------------------------
__global__ __launch_bounds__(512, 2) void lstm_rec(
    const f16* __restrict__ Wh_t, const f16* __restrict__ Wfrag,
    const f16* __restrict__ X, float* __restrict__ out)
{
  __shared__ f16  Wl[65536];      // 128 KB: [2 kfi][64 nt][64 lane][8]
  __shared__ f16  hbuf[2][256];
  __shared__ float act[4][256];
  __shared__ f16  xl[2][1024];

  int b   = blockIdx.x;
  int tid = threadIdx.x;
  int w = tid >> 6, l = tid & 63, lr = l & 15, lg = l >> 4;
  int g = w >> 1;                 // gate for this wave (0=i,1=f,2=g,3=o)

  // load LDS W slice (linear copy)
  {
    const f16x8* srcp = (const f16x8*)Wfrag;
    f16x8* dstp = (f16x8*)Wl;
    #pragma unroll
    for (int i = 0; i < 16; ++i) dstp[tid + i*512] = srcp[tid + i*512];
  }
  // load register B-fragments for k < 192
  f16x8 WB[8][6];
  #pragma unroll
  for (int nt = 0; nt < 8; ++nt) {
    int col = (w*8+nt)*16 + lr;
    const f16* basep = Wh_t + (size_t)col*256 + lg*8;
    #pragma unroll
    for (int kf = 0; kf < 6; ++kf) WB[nt][kf] = *(const f16x8*)(basep + kf*32);
  }
  // init h = 0 (both buffers), stage x_0
  ((f16*)hbuf)[tid] = (f16)0.f;
  ((uint32_t*)xl[0])[tid] = *(const uint32_t*)(X + (size_t)b*NC + (size_t)tid*2);
  float c = 0.f;
  __syncthreads();

  for (int t = 0; t < SEQ; ++t) {
    int cur = t & 1;
    // C init = x_t (includes bias from phase 1), replicated across rows
    f32x4 cf[8];
    #pragma unroll
    for (int nt = 0; nt < 8; ++nt) {
      float xv = (float)xl[cur][(w*8+nt)*16 + lr];
      cf[nt] = (f32x4){xv, xv, xv, xv};
    }
    // prefetch x_{t+1} into the other buffer (hidden under MFMAs)
    if (t < SEQ-1) {
      ((uint32_t*)xl[cur^1])[tid] =
        *(const uint32_t*)(X + (size_t)(t+1)*BATCH*NC + (size_t)b*NC + (size_t)tid*2);
    }
    // k < 192: B from registers
    #pragma unroll
    for (int kf = 0; kf < 6; ++kf) {
      f16x8 ha = *(const f16x8*)(&hbuf[cur][kf*32 + lg*8]);
      #pragma unroll
      for (int nt = 0; nt < 8; ++nt)
        cf[nt] = __builtin_amdgcn_mfma_f32_16x16x32_f16(ha, WB[nt][kf], cf[nt], 0, 0, 0);
    }
    // k in [192,256): B from LDS (lane-stride-16, conflict-free)
    #pragma unroll
    for (int kfi = 0; kfi < 2; ++kfi) {
      f16x8 ha = *(const f16x8*)(&hbuf[cur][(6+kfi)*32 + lg*8]);
      #pragma unroll
      for (int nt = 0; nt < 8; ++nt) {
        f16x8 wb = *(const f16x8*)(&Wl[(size_t)((kfi*64 + (w*8+nt))*64 + l)*8]);
        cf[nt] = __builtin_amdgcn_mfma_f32_16x16x32_f16(ha, wb, cf[nt], 0, 0, 0);
      }
    }
    // activations (all C rows equal -> use reg 0; lanes 0-15 hold distinct cols)
    #pragma unroll
    for (int nt = 0; nt < 8; ++nt) {
      float y = cf[nt][0];
      float a = (g == 2) ? tanhf(y) : 1.f/(1.f + expf(-y));
      if (l < 16) act[g][(((w*8+nt)*16) & 255) + lr] = a;
    }
    __syncthreads();
    // c/h update by threads 0..255 (unit = tid)
    if (tid < 256) {
      float i_ = act[0][tid], f_ = act[1][tid], gg = act[2][tid], o_ = act[3][tid];
      c = f_*c + i_*gg;
      float h = o_*tanhf(c);
      out[(size_t)t*(BATCH*HID) + (size_t)b*HID + tid] = h;
      hbuf[cur^1][tid] = (f16)h;
    }
    __syncthreads();
  }
}

// ---------------------------------------------------------------------------
extern "C" void kernel_launch(void* const* d_in, const int* in_sizes, int n_in,
                              void* d_out, int out_size, void* d_ws, size_t ws_size,
                              hipStream_t stream) {
  const float* emb = (const float*)d_in[0];
  const float* Wix = (const float*)d_in[1];
  const float* Wih = (const float*)d_in[2];
  const float* bi  = (const float*)d_in[3];
  const float* Wfx = (const float*)d_in[4];
  const float* Wfh = (const float*)d_in[5];
  const float* bf  = (const float*)d_in[6];
  const float* Wgx = (const float*)d_in[7];
  const float* Wgh = (const float*)d_in[8];
  const float* bg  = (const float*)d_in[9];
  const float* Wox = (const float*)d_in[10];
  const float* Woh = (const float*)d_in[11];
  const float* bo  = (const float*)d_in[12];

  char* ws = (char*)d_ws;
  f16* Wx_t  = (f16*)(ws);                    //   524288 B
  f16* Wh_t  = (f16*)(ws + 524288);           //   524288 B
  f16* Wfrag = (f16*)(ws + 1048576);          //   131072 B
  f16* Xp    = (f16*)(ws + 1179648);          // 268435456 B  (f16 x-projections)

  prep_w  <<<288,   256, 0, stream>>>(Wix, Wih, Wfx, Wfh, Wgx, Wgh, Wox, Woh,
                                      Wx_t, Wh_t, Wfrag);
  gemm_x  <<<32768, 256, 0, stream>>>(emb, Wx_t, bi, bf, bg, bo, Xp);
  lstm_rec<<<64,    512, 0, stream>>>(Wh_t, Wfrag, Xp, (float*)d_out);
}

// Round 3
// 6044.352 us; speedup vs baseline: 1.1790x; 1.1790x over previous
//
#include <hip/hip_runtime.h>

typedef _Float16 f16;
typedef _Float16 f16x8 __attribute__((ext_vector_type(8)));
typedef float    f32x4 __attribute__((ext_vector_type(4)));

#define SEQ   2048
#define BATCH 64
#define EMBED 256
#define HID   256
#define NC    1024            // 4 gates * HID

// fast transcendentals (1-instr HW ops; ~1ulp, fine vs f16-weight noise)
__device__ __forceinline__ float fexp2(float x){ float r; asm("v_exp_f32 %0, %1" : "=v"(r) : "v"(x)); return r; }
__device__ __forceinline__ float frcp (float x){ float r; asm("v_rcp_f32 %0, %1" : "=v"(r) : "v"(x)); return r; }
__device__ __forceinline__ float sigm_f(float y){ return frcp(1.f + fexp2(y * -1.44269504f)); }
__device__ __forceinline__ float tanh_f(float y){ return 2.f*frcp(1.f + fexp2(y * -2.88539009f)) - 1.f; }

__device__ __forceinline__ void gload_lds4(const void* g, void* s) {
  __builtin_amdgcn_global_load_lds((const __attribute__((address_space(1))) void*)g,
                                   (__attribute__((address_space(3))) void*)s, 4, 0, 0);
}

// ---------------------------------------------------------------------------
// prep_w: build f16 weight layouts in workspace (unchanged).
// ---------------------------------------------------------------------------
__global__ __launch_bounds__(256) void prep_w(
    const float* __restrict__ Wix, const float* __restrict__ Wih,
    const float* __restrict__ Wfx, const float* __restrict__ Wfh,
    const float* __restrict__ Wgx, const float* __restrict__ Wgh,
    const float* __restrict__ Wox, const float* __restrict__ Woh,
    f16* __restrict__ Wx_t, f16* __restrict__ Wh_t, f16* __restrict__ Wfrag)
{
  int tid = blockIdx.x*256 + threadIdx.x;
  const float* WX[4] = {Wix, Wfx, Wgx, Wox};
  const float* WH[4] = {Wih, Wfh, Wgh, Woh};
  if (tid < 65536) {
    int which = tid >> 15;
    int j  = (tid >> 5) & 1023;
    int ko = tid & 31;
    const float* src = (which ? WH : WX)[j >> 8];
    int u = j & 255;
    f16x8 v;
    #pragma unroll
    for (int q = 0; q < 8; ++q) v[q] = (f16)src[(ko*8+q)*HID + u];
    *(f16x8*)((which ? Wh_t : Wx_t) + (size_t)j*256 + ko*8) = v;
  } else if (tid < 65536 + 8192) {
    int r   = tid - 65536;
    int l   = r & 63, gt = (r >> 6) & 63, kfi = r >> 12;
    int col = gt*16 + (l & 15);
    int kbase = 192 + kfi*32 + (l >> 4)*8;
    const float* src = WH[col >> 8];
    int u = col & 255;
    f16x8 v;
    #pragma unroll
    for (int q = 0; q < 8; ++q) v[q] = (f16)src[(kbase+q)*HID + u];
    *(f16x8*)(Wfrag + (size_t)r*8) = v;
  }
}

// ---------------------------------------------------------------------------
// gemm_x (unchanged)
// ---------------------------------------------------------------------------
__global__ __launch_bounds__(256) void gemm_x(
    const float* __restrict__ emb, const f16* __restrict__ Bt,
    const float* __restrict__ b0, const float* __restrict__ b1,
    const float* __restrict__ b2, const float* __restrict__ b3,
    f16* __restrict__ Xo)
{
  __shared__ f16 Al[64*256];
  __shared__ f16 Bl[64*256];
  int wg = blockIdx.x;
  int R0 = (wg >> 4) * 64;
  int C0 = (wg & 15) * 64;
  int tid = threadIdx.x;

  #pragma unroll
  for (int j = 0; j < 8; ++j) {
    int c = tid + j*256; int row = c >> 5, ci = c & 31;
    const float* ap = emb + (size_t)(R0+row)*EMBED + ci*8;
    f32x4 a0 = *(const f32x4*)ap;
    f32x4 a1 = *(const f32x4*)(ap + 4);
    f16x8 v;
    #pragma unroll
    for (int q = 0; q < 4; ++q) { v[q] = (f16)a0[q]; v[q+4] = (f16)a1[q]; }
    *(f16x8*)((char*)Al + row*512 + ((ci*16) ^ ((row&7)<<4))) = v;
    f16x8 vb = *(const f16x8*)(Bt + (size_t)(C0+row)*256 + ci*8);
    *(f16x8*)((char*)Bl + row*512 + ((ci*16) ^ ((row&7)<<4))) = vb;
  }
  __syncthreads();

  int w = tid >> 6, l = tid & 63, lr = l & 15, lg = l >> 4;
  const float* bp = (C0 < 256) ? b0 : (C0 < 512) ? b1 : (C0 < 768) ? b2 : b3;
  int ub = (C0 & 255) + lr;
  f32x4 cf[4];
  #pragma unroll
  for (int nt = 0; nt < 4; ++nt) { float bv = bp[ub + nt*16]; cf[nt] = (f32x4){bv,bv,bv,bv}; }

  #pragma unroll
  for (int kf = 0; kf < 8; ++kf) {
    int arow = w*16 + lr;
    f16x8 af = *(const f16x8*)((char*)Al + arow*512 + ((kf*64 + lg*16) ^ ((arow&7)<<4)));
    #pragma unroll
    for (int nt = 0; nt < 4; ++nt) {
      int brow = nt*16 + lr;
      f16x8 bf = *(const f16x8*)((char*)Bl + brow*512 + ((kf*64 + lg*16) ^ ((brow&7)<<4)));
      cf[nt] = __builtin_amdgcn_mfma_f32_16x16x32_f16(af, bf, cf[nt], 0, 0, 0);
    }
  }
  #pragma unroll
  for (int nt = 0; nt < 4; ++nt)
    #pragma unroll
    for (int r = 0; r < 4; ++r) {
      int row = R0 + w*16 + lg*4 + r;
      int col = C0 + nt*16 + lr;
      Xo[(size_t)row*NC + col] = (f16)cf[nt][r];
    }
}

// ---------------------------------------------------------------------------
// lstm_rec: one WG per batch (64 WGs), 512 threads (8 waves, 2/SIMD).
// Per step: y[1024] = x_t + h @ Wh via MFMA matvec (h replicated in A rows).
// Wh k<192 in per-lane B-frag registers (WB); k in [192,256) from 128 KB LDS.
// LDS/hbuf reads are plain C++ loads (compiler schedules lgkmcnt) — R1-style.
// Counted-wait barrier discipline (the R2 change, now debugged):
//   barrier1: lgkmcnt(0) only             (act visible)
//   barrier2: vmcnt(1) lgkmcnt(0)         (hbuf + x(t+1) visible; x(t+2)
//                                          load stays in flight)
// out store issued AFTER barrier2 -> ack hidden under next step.
// x prefetched 2 steps ahead via global_load_lds into 3 rotating LDS bufs.
// ---------------------------------------------------------------------------
__global__ __launch_bounds__(512, 2) void lstm_rec(
    const f16* __restrict__ Wh_t, const f16* __restrict__ Wfrag,
    const f16* __restrict__ X, float* __restrict__ out)
{
  __shared__ f16   Wl[65536];        // 128 KB: [2 kfi][64 nt][64 lane][8]
  __shared__ f16   hbuf[2][256];
  __shared__ float act[4][256];
  __shared__ f16   xl[3][1024];      // rotating x buffers

  int b   = blockIdx.x;
  int tid = threadIdx.x;
  int w = tid >> 6, l = tid & 63, lr = l & 15, lg = l >> 4;
  int g = w >> 1;

  // ---- prologue ----
  gload_lds4(X + (size_t)b*NC + tid*2,           &xl[0][w*128]);
  gload_lds4(X + (size_t)(BATCH + b)*NC + tid*2, &xl[1][w*128]);

  {
    const f16x8* srcp = (const f16x8*)Wfrag;
    f16x8* dstp = (f16x8*)Wl;
    #pragma unroll
    for (int i = 0; i < 16; ++i) dstp[tid + i*512] = srcp[tid + i*512];
  }
  f16x8 WB[8][6];
  #pragma unroll
  for (int nt = 0; nt < 8; ++nt) {
    int col = (w*8+nt)*16 + lr;
    const f16* basep = Wh_t + (size_t)col*256 + lg*8;
    #pragma unroll
    for (int kf = 0; kf < 6; ++kf) WB[nt][kf] = *(const f16x8*)(basep + kf*32);
  }
  ((f16*)hbuf)[tid] = (f16)0.f;
  float c = 0.f;

  asm volatile("s_waitcnt vmcnt(0) lgkmcnt(0)" ::: "memory");
  __builtin_amdgcn_s_barrier();

  int xc = 0;   // buffer holding x_t
  for (int t = 0; t < SEQ; ++t) {
    int cur = t & 1;
    // A: issue prefetch for t+2 (newest in-flight op; survives barrier2)
    if (t + 2 < SEQ) {
      int xn2 = (xc == 0) ? 2 : xc - 1;
      gload_lds4(X + ((size_t)(t+2)*BATCH + b)*NC + tid*2, &xl[xn2][w*128]);
    }
    // B: cf init from x_t
    const f16* xp = xl[xc];
    f32x4 cf[8];
    #pragma unroll
    for (int nt = 0; nt < 8; ++nt) {
      float xv = (float)xp[(w*8+nt)*16 + lr];
      cf[nt] = (f32x4){xv, xv, xv, xv};
    }
    // C: k < 192, B-operands from registers
    #pragma unroll
    for (int kf = 0; kf < 6; ++kf) {
      f16x8 ha = *(const f16x8*)(&hbuf[cur][kf*32 + lg*8]);
      #pragma unroll
      for (int nt = 0; nt < 8; ++nt)
        cf[nt] = __builtin_amdgcn_mfma_f32_16x16x32_f16(ha, WB[nt][kf], cf[nt], 0, 0, 0);
    }
    // D: k in [192,256), B-operands streamed from LDS (lane-stride-16, conflict-free)
    #pragma unroll
    for (int kfi = 0; kfi < 2; ++kfi) {
      f16x8 ha = *(const f16x8*)(&hbuf[cur][(6+kfi)*32 + lg*8]);
      #pragma unroll
      for (int nt = 0; nt < 8; ++nt) {
        f16x8 wb = *(const f16x8*)(&Wl[(size_t)((kfi*64 + (w*8+nt))*64 + l)*8]);
        cf[nt] = __builtin_amdgcn_mfma_f32_16x16x32_f16(ha, wb, cf[nt], 0, 0, 0);
      }
    }
    // E: activations (1-instr HW transcendentals)
    #pragma unroll
    for (int nt = 0; nt < 8; ++nt) {
      float y = cf[nt][0];
      float a = (g == 2) ? tanh_f(y) : sigm_f(y);
      if (l < 16) act[g][(((w*8+nt)*16) & 255) + lr] = a;
    }
    asm volatile("s_waitcnt lgkmcnt(0)" ::: "memory");
    __builtin_amdgcn_s_barrier();

    // F: c/h update (threads 0..255; unit = tid)
    float hnew = 0.f;
    if (tid < 256) {
      float i_ = act[0][tid], f_ = act[1][tid], gg = act[2][tid], o_ = act[3][tid];
      c = f_*c + i_*gg;
      hnew = o_*tanh_f(c);
      hbuf[cur ^ 1][tid] = (f16)hnew;
    }
    asm volatile("s_waitcnt vmcnt(1) lgkmcnt(0)" ::: "memory");
    __builtin_amdgcn_s_barrier();

    // G: out store after barrier (ack hidden under next step)
    if (tid < 256) out[((size_t)t*BATCH + b)*HID + tid] = hnew;

    xc = (xc == 2) ? 0 : xc + 1;
  }
}

// ---------------------------------------------------------------------------
extern "C" void kernel_launch(void* const* d_in, const int* in_sizes, int n_in,
                              void* d_out, int out_size, void* d_ws, size_t ws_size,
                              hipStream_t stream) {
  const float* emb = (const float*)d_in[0];
  const float* Wix = (const float*)d_in[1];
  const float* Wih = (const float*)d_in[2];
  const float* bi  = (const float*)d_in[3];
  const float* Wfx = (const float*)d_in[4];
  const float* Wfh = (const float*)d_in[5];
  const float* bf  = (const float*)d_in[6];
  const float* Wgx = (const float*)d_in[7];
  const float* Wgh = (const float*)d_in[8];
  const float* bg  = (const float*)d_in[9];
  const float* Wox = (const float*)d_in[10];
  const float* Woh = (const float*)d_in[11];
  const float* bo  = (const float*)d_in[12];

  char* ws = (char*)d_ws;
  f16* Wx_t  = (f16*)(ws);
  f16* Wh_t  = (f16*)(ws + 524288);
  f16* Wfrag = (f16*)(ws + 1048576);
  f16* Xp    = (f16*)(ws + 1179648);

  prep_w  <<<288,   256, 0, stream>>>(Wix, Wih, Wfx, Wfh, Wgx, Wgh, Wox, Woh,
                                      Wx_t, Wh_t, Wfrag);
  gemm_x  <<<32768, 256, 0, stream>>>(emb, Wx_t, bi, bf, bg, bo, Xp);
  lstm_rec<<<64,    512, 0, stream>>>(Wh_t, Wfrag, Xp, (float*)d_out);
}

// Round 4
// 6030.336 us; speedup vs baseline: 1.1817x; 1.0023x over previous
//
#include <hip/hip_runtime.h>

typedef _Float16 f16;
typedef _Float16 f16x8 __attribute__((ext_vector_type(8)));
typedef float    f32x4 __attribute__((ext_vector_type(4)));

#define SEQ   2048
#define BATCH 64
#define EMBED 256
#define HID   256
#define NC    1024            // 4 gates * HID

// fast transcendentals (1-instr HW ops; ~1ulp, fine vs f16-weight noise)
__device__ __forceinline__ float fexp2(float x){ float r; asm("v_exp_f32 %0, %1" : "=v"(r) : "v"(x)); return r; }
__device__ __forceinline__ float frcp (float x){ float r; asm("v_rcp_f32 %0, %1" : "=v"(r) : "v"(x)); return r; }
__device__ __forceinline__ float sigm_f(float y){ return frcp(1.f + fexp2(y * -1.44269504f)); }
__device__ __forceinline__ float tanh_f(float y){ return 2.f*frcp(1.f + fexp2(y * -2.88539009f)) - 1.f; }

__device__ __forceinline__ void gload_lds4(const void* g, void* s) {
  __builtin_amdgcn_global_load_lds((const __attribute__((address_space(1))) void*)g,
                                   (__attribute__((address_space(3))) void*)s, 4, 0, 0);
}

// ---------------------------------------------------------------------------
// prep_w: build f16 weight layouts in workspace (unchanged).
// ---------------------------------------------------------------------------
__global__ __launch_bounds__(256) void prep_w(
    const float* __restrict__ Wix, const float* __restrict__ Wih,
    const float* __restrict__ Wfx, const float* __restrict__ Wfh,
    const float* __restrict__ Wgx, const float* __restrict__ Wgh,
    const float* __restrict__ Wox, const float* __restrict__ Woh,
    f16* __restrict__ Wx_t, f16* __restrict__ Wh_t, f16* __restrict__ Wfrag)
{
  int tid = blockIdx.x*256 + threadIdx.x;
  const float* WX[4] = {Wix, Wfx, Wgx, Wox};
  const float* WH[4] = {Wih, Wfh, Wgh, Woh};
  if (tid < 65536) {
    int which = tid >> 15;
    int j  = (tid >> 5) & 1023;
    int ko = tid & 31;
    const float* src = (which ? WH : WX)[j >> 8];
    int u = j & 255;
    f16x8 v;
    #pragma unroll
    for (int q = 0; q < 8; ++q) v[q] = (f16)src[(ko*8+q)*HID + u];
    *(f16x8*)((which ? Wh_t : Wx_t) + (size_t)j*256 + ko*8) = v;
  } else if (tid < 65536 + 8192) {
    int r   = tid - 65536;
    int l   = r & 63, gt = (r >> 6) & 63, kfi = r >> 12;
    int col = gt*16 + (l & 15);
    int kbase = 192 + kfi*32 + (l >> 4)*8;
    const float* src = WH[col >> 8];
    int u = col & 255;
    f16x8 v;
    #pragma unroll
    for (int q = 0; q < 8; ++q) v[q] = (f16)src[(kbase+q)*HID + u];
    *(f16x8*)(Wfrag + (size_t)r*8) = v;
  }
}

// ---------------------------------------------------------------------------
// gemm_x (unchanged)
// ---------------------------------------------------------------------------
__global__ __launch_bounds__(256) void gemm_x(
    const float* __restrict__ emb, const f16* __restrict__ Bt,
    const float* __restrict__ b0, const float* __restrict__ b1,
    const float* __restrict__ b2, const float* __restrict__ b3,
    f16* __restrict__ Xo)
{
  __shared__ f16 Al[64*256];
  __shared__ f16 Bl[64*256];
  int wg = blockIdx.x;
  int R0 = (wg >> 4) * 64;
  int C0 = (wg & 15) * 64;
  int tid = threadIdx.x;

  #pragma unroll
  for (int j = 0; j < 8; ++j) {
    int c = tid + j*256; int row = c >> 5, ci = c & 31;
    const float* ap = emb + (size_t)(R0+row)*EMBED + ci*8;
    f32x4 a0 = *(const f32x4*)ap;
    f32x4 a1 = *(const f32x4*)(ap + 4);
    f16x8 v;
    #pragma unroll
    for (int q = 0; q < 4; ++q) { v[q] = (f16)a0[q]; v[q+4] = (f16)a1[q]; }
    *(f16x8*)((char*)Al + row*512 + ((ci*16) ^ ((row&7)<<4))) = v;
    f16x8 vb = *(const f16x8*)(Bt + (size_t)(C0+row)*256 + ci*8);
    *(f16x8*)((char*)Bl + row*512 + ((ci*16) ^ ((row&7)<<4))) = vb;
  }
  __syncthreads();

  int w = tid >> 6, l = tid & 63, lr = l & 15, lg = l >> 4;
  const float* bp = (C0 < 256) ? b0 : (C0 < 512) ? b1 : (C0 < 768) ? b2 : b3;
  int ub = (C0 & 255) + lr;
  f32x4 cf[4];
  #pragma unroll
  for (int nt = 0; nt < 4; ++nt) { float bv = bp[ub + nt*16]; cf[nt] = (f32x4){bv,bv,bv,bv}; }

  #pragma unroll
  for (int kf = 0; kf < 8; ++kf) {
    int arow = w*16 + lr;
    f16x8 af = *(const f16x8*)((char*)Al + arow*512 + ((kf*64 + lg*16) ^ ((arow&7)<<4)));
    #pragma unroll
    for (int nt = 0; nt < 4; ++nt) {
      int brow = nt*16 + lr;
      f16x8 bf = *(const f16x8*)((char*)Bl + brow*512 + ((kf*64 + lg*16) ^ ((brow&7)<<4)));
      cf[nt] = __builtin_amdgcn_mfma_f32_16x16x32_f16(af, bf, cf[nt], 0, 0, 0);
    }
  }
  #pragma unroll
  for (int nt = 0; nt < 4; ++nt)
    #pragma unroll
    for (int r = 0; r < 4; ++r) {
      int row = R0 + w*16 + lg*4 + r;
      int col = C0 + nt*16 + lr;
      Xo[(size_t)row*NC + col] = (f16)cf[nt][r];
    }
}

// ---------------------------------------------------------------------------
// lstm_rec: one WG per batch (64 WGs), 512 threads (8 waves, 2/SIMD).
// Per step: y[1024] = x_t + h @ Wh via MFMA matvec (h replicated in A rows).
// Wh k<192 in per-lane B-frag registers (WB, 192 VGPR); k in [192,256) from
// 128 KB LDS. REGISTER BUDGET IS THE POINT: WB+cf+misc ~ 240 regs, needs the
// 256-cap (2 waves/SIMD). amdgpu_waves_per_eu(2) pins the allocator there —
// R3's __launch_bounds__(512,2) budgeted 128 regs and spilled WB to scratch
// (L2 reload ~7000 cy/step == the whole R3 runtime).
// Counted-wait barriers:
//   barrier1: lgkmcnt(0)            (act visible)
//   barrier2: vmcnt(1) lgkmcnt(0)   (hbuf + x(t+1) visible; x(t+2) in flight)
// out store after barrier2; x prefetched 2 ahead via global_load_lds, 3 bufs.
// ---------------------------------------------------------------------------
__global__ __launch_bounds__(512) __attribute__((amdgpu_waves_per_eu(2)))
void lstm_rec(
    const f16* __restrict__ Wh_t, const f16* __restrict__ Wfrag,
    const f16* __restrict__ X, float* __restrict__ out)
{
  __shared__ f16   Wl[65536];        // 128 KB: [2 kfi][64 nt][64 lane][8]
  __shared__ f16   hbuf[2][256];
  __shared__ float act[4][256];
  __shared__ f16   xl[3][1024];      // rotating x buffers

  int b   = blockIdx.x;
  int tid = threadIdx.x;
  int w = tid >> 6, l = tid & 63, lr = l & 15, lg = l >> 4;
  int g = w >> 1;

  // ---- prologue ----
  gload_lds4(X + (size_t)b*NC + tid*2,           &xl[0][w*128]);
  gload_lds4(X + (size_t)(BATCH + b)*NC + tid*2, &xl[1][w*128]);

  {
    const f16x8* srcp = (const f16x8*)Wfrag;
    f16x8* dstp = (f16x8*)Wl;
    #pragma unroll
    for (int i = 0; i < 16; ++i) dstp[tid + i*512] = srcp[tid + i*512];
  }
  f16x8 WB[8][6];
  #pragma unroll
  for (int nt = 0; nt < 8; ++nt) {
    int col = (w*8+nt)*16 + lr;
    const f16* basep = Wh_t + (size_t)col*256 + lg*8;
    #pragma unroll
    for (int kf = 0; kf < 6; ++kf) WB[nt][kf] = *(const f16x8*)(basep + kf*32);
  }
  ((f16*)hbuf)[tid] = (f16)0.f;
  float c = 0.f;

  asm volatile("s_waitcnt vmcnt(0) lgkmcnt(0)" ::: "memory");
  __builtin_amdgcn_s_barrier();

  int xc = 0;   // buffer holding x_t
  for (int t = 0; t < SEQ; ++t) {
    int cur = t & 1;
    // A: issue prefetch for t+2 (newest in-flight op; survives barrier2)
    if (t + 2 < SEQ) {
      int xn2 = (xc == 0) ? 2 : xc - 1;
      gload_lds4(X + ((size_t)(t+2)*BATCH + b)*NC + tid*2, &xl[xn2][w*128]);
    }
    // B: cf init from x_t
    const f16* xp = xl[xc];
    f32x4 cf[8];
    #pragma unroll
    for (int nt = 0; nt < 8; ++nt) {
      float xv = (float)xp[(w*8+nt)*16 + lr];
      cf[nt] = (f32x4){xv, xv, xv, xv};
    }
    // C: k < 192, B-operands from registers
    #pragma unroll
    for (int kf = 0; kf < 6; ++kf) {
      f16x8 ha = *(const f16x8*)(&hbuf[cur][kf*32 + lg*8]);
      #pragma unroll
      for (int nt = 0; nt < 8; ++nt)
        cf[nt] = __builtin_amdgcn_mfma_f32_16x16x32_f16(ha, WB[nt][kf], cf[nt], 0, 0, 0);
    }
    // D: k in [192,256), B-operands streamed from LDS (conflict-free)
    #pragma unroll
    for (int kfi = 0; kfi < 2; ++kfi) {
      f16x8 ha = *(const f16x8*)(&hbuf[cur][(6+kfi)*32 + lg*8]);
      #pragma unroll
      for (int nt = 0; nt < 8; ++nt) {
        f16x8 wb = *(const f16x8*)(&Wl[(size_t)((kfi*64 + (w*8+nt))*64 + l)*8]);
        cf[nt] = __builtin_amdgcn_mfma_f32_16x16x32_f16(ha, wb, cf[nt], 0, 0, 0);
      }
    }
    // E: activations (1-instr HW transcendentals)
    #pragma unroll
    for (int nt = 0; nt < 8; ++nt) {
      float y = cf[nt][0];
      float a = (g == 2) ? tanh_f(y) : sigm_f(y);
      if (l < 16) act[g][(((w*8+nt)*16) & 255) + lr] = a;
    }
    asm volatile("s_waitcnt lgkmcnt(0)" ::: "memory");
    __builtin_amdgcn_s_barrier();

    // F: c/h update (threads 0..255; unit = tid)
    float hnew = 0.f;
    if (tid < 256) {
      float i_ = act[0][tid], f_ = act[1][tid], gg = act[2][tid], o_ = act[3][tid];
      c = f_*c + i_*gg;
      hnew = o_*tanh_f(c);
      hbuf[cur ^ 1][tid] = (f16)hnew;
    }
    asm volatile("s_waitcnt vmcnt(1) lgkmcnt(0)" ::: "memory");
    __builtin_amdgcn_s_barrier();

    // G: out store after barrier (ack hidden under next step)
    if (tid < 256) out[((size_t)t*BATCH + b)*HID + tid] = hnew;

    xc = (xc == 2) ? 0 : xc + 1;
  }
}

// ---------------------------------------------------------------------------
extern "C" void kernel_launch(void* const* d_in, const int* in_sizes, int n_in,
                              void* d_out, int out_size, void* d_ws, size_t ws_size,
                              hipStream_t stream) {
  const float* emb = (const float*)d_in[0];
  const float* Wix = (const float*)d_in[1];
  const float* Wih = (const float*)d_in[2];
  const float* bi  = (const float*)d_in[3];
  const float* Wfx = (const float*)d_in[4];
  const float* Wfh = (const float*)d_in[5];
  const float* bf  = (const float*)d_in[6];
  const float* Wgx = (const float*)d_in[7];
  const float* Wgh = (const float*)d_in[8];
  const float* bg  = (const float*)d_in[9];
  const float* Wox = (const float*)d_in[10];
  const float* Woh = (const float*)d_in[11];
  const float* bo  = (const float*)d_in[12];

  char* ws = (char*)d_ws;
  f16* Wx_t  = (f16*)(ws);
  f16* Wh_t  = (f16*)(ws + 524288);
  f16* Wfrag = (f16*)(ws + 1048576);
  f16* Xp    = (f16*)(ws + 1179648);

  prep_w  <<<288,   256, 0, stream>>>(Wix, Wih, Wfx, Wfh, Wgx, Wgh, Wox, Woh,
                                      Wx_t, Wh_t, Wfrag);
  gemm_x  <<<32768, 256, 0, stream>>>(emb, Wx_t, bi, bf, bg, bo, Xp);
  lstm_rec<<<64,    512, 0, stream>>>(Wh_t, Wfrag, Xp, (float*)d_out);
}

// Round 5
// 4655.261 us; speedup vs baseline: 1.5308x; 1.2954x over previous
//
#include <hip/hip_runtime.h>

typedef _Float16 f16;
typedef _Float16 f16x8 __attribute__((ext_vector_type(8)));
typedef float    f32x4 __attribute__((ext_vector_type(4)));

#define SEQ   2048
#define BATCH 64
#define EMBED 256
#define HID   256
#define NC    1024            // 4 gates * HID

// fast transcendentals (1-instr HW ops)
__device__ __forceinline__ float fexp2(float x){ float r; asm("v_exp_f32 %0, %1" : "=v"(r) : "v"(x)); return r; }
__device__ __forceinline__ float frcp (float x){ float r; asm("v_rcp_f32 %0, %1" : "=v"(r) : "v"(x)); return r; }
__device__ __forceinline__ float sigm_f(float y){ return frcp(1.f + fexp2(y * -1.44269504f)); }
__device__ __forceinline__ float tanh_f(float y){ return 2.f*frcp(1.f + fexp2(y * -2.88539009f)) - 1.f; }

__device__ __forceinline__ void gload_lds4(const void* g, void* s) {
  __builtin_amdgcn_global_load_lds((const __attribute__((address_space(1))) void*)g,
                                   (__attribute__((address_space(3))) void*)s, 4, 0, 0);
}

// ---------------------------------------------------------------------------
// prep_w (unchanged)
// ---------------------------------------------------------------------------
__global__ __launch_bounds__(256) void prep_w(
    const float* __restrict__ Wix, const float* __restrict__ Wih,
    const float* __restrict__ Wfx, const float* __restrict__ Wfh,
    const float* __restrict__ Wgx, const float* __restrict__ Wgh,
    const float* __restrict__ Wox, const float* __restrict__ Woh,
    f16* __restrict__ Wx_t, f16* __restrict__ Wh_t, f16* __restrict__ Wfrag)
{
  int tid = blockIdx.x*256 + threadIdx.x;
  const float* WX[4] = {Wix, Wfx, Wgx, Wox};
  const float* WH[4] = {Wih, Wfh, Wgh, Woh};
  if (tid < 65536) {
    int which = tid >> 15;
    int j  = (tid >> 5) & 1023;
    int ko = tid & 31;
    const float* src = (which ? WH : WX)[j >> 8];
    int u = j & 255;
    f16x8 v;
    #pragma unroll
    for (int q = 0; q < 8; ++q) v[q] = (f16)src[(ko*8+q)*HID + u];
    *(f16x8*)((which ? Wh_t : Wx_t) + (size_t)j*256 + ko*8) = v;
  } else if (tid < 65536 + 8192) {
    int r   = tid - 65536;
    int l   = r & 63, gt = (r >> 6) & 63, kfi = r >> 12;
    int col = gt*16 + (l & 15);
    int kbase = 192 + kfi*32 + (l >> 4)*8;
    const float* src = WH[col >> 8];
    int u = col & 255;
    f16x8 v;
    #pragma unroll
    for (int q = 0; q < 8; ++q) v[q] = (f16)src[(kbase+q)*HID + u];
    *(f16x8*)(Wfrag + (size_t)r*8) = v;
  }
}

// ---------------------------------------------------------------------------
// gemm_x (unchanged)
// ---------------------------------------------------------------------------
__global__ __launch_bounds__(256) void gemm_x(
    const float* __restrict__ emb, const f16* __restrict__ Bt,
    const float* __restrict__ b0, const float* __restrict__ b1,
    const float* __restrict__ b2, const float* __restrict__ b3,
    f16* __restrict__ Xo)
{
  __shared__ f16 Al[64*256];
  __shared__ f16 Bl[64*256];
  int wg = blockIdx.x;
  int R0 = (wg >> 4) * 64;
  int C0 = (wg & 15) * 64;
  int tid = threadIdx.x;

  #pragma unroll
  for (int j = 0; j < 8; ++j) {
    int c = tid + j*256; int row = c >> 5, ci = c & 31;
    const float* ap = emb + (size_t)(R0+row)*EMBED + ci*8;
    f32x4 a0 = *(const f32x4*)ap;
    f32x4 a1 = *(const f32x4*)(ap + 4);
    f16x8 v;
    #pragma unroll
    for (int q = 0; q < 4; ++q) { v[q] = (f16)a0[q]; v[q+4] = (f16)a1[q]; }
    *(f16x8*)((char*)Al + row*512 + ((ci*16) ^ ((row&7)<<4))) = v;
    f16x8 vb = *(const f16x8*)(Bt + (size_t)(C0+row)*256 + ci*8);
    *(f16x8*)((char*)Bl + row*512 + ((ci*16) ^ ((row&7)<<4))) = vb;
  }
  __syncthreads();

  int w = tid >> 6, l = tid & 63, lr = l & 15, lg = l >> 4;
  const float* bp = (C0 < 256) ? b0 : (C0 < 512) ? b1 : (C0 < 768) ? b2 : b3;
  int ub = (C0 & 255) + lr;
  f32x4 cf[4];
  #pragma unroll
  for (int nt = 0; nt < 4; ++nt) { float bv = bp[ub + nt*16]; cf[nt] = (f32x4){bv,bv,bv,bv}; }

  #pragma unroll
  for (int kf = 0; kf < 8; ++kf) {
    int arow = w*16 + lr;
    f16x8 af = *(const f16x8*)((char*)Al + arow*512 + ((kf*64 + lg*16) ^ ((arow&7)<<4)));
    #pragma unroll
    for (int nt = 0; nt < 4; ++nt) {
      int brow = nt*16 + lr;
      f16x8 bf = *(const f16x8*)((char*)Bl + brow*512 + ((kf*64 + lg*16) ^ ((brow&7)<<4)));
      cf[nt] = __builtin_amdgcn_mfma_f32_16x16x32_f16(af, bf, cf[nt], 0, 0, 0);
    }
  }
  #pragma unroll
  for (int nt = 0; nt < 4; ++nt)
    #pragma unroll
    for (int r = 0; r < 4; ++r) {
      int row = R0 + w*16 + lg*4 + r;
      int col = C0 + nt*16 + lr;
      Xo[(size_t)row*NC + col] = (f16)cf[nt][r];
    }
}

// ---------------------------------------------------------------------------
// lstm_rec: one WG per batch (64 WGs), 512 threads (8 waves, 2/SIMD).
// Wave w, tile nt: col(nt,lr) = (nt>>1)*256 + w*32 + (nt&1)*16 + lr — each
// lane l<16 owns units {w*32+lr, w*32+16+lr} with ALL FOUR gates in its own
// cf[0..7][0] -> lane-local c/h update, no act[] LDS, ONE barrier per step.
// Wh k<192 in laundered B-frag registers WB (asm "+v" blocks the compiler
// from rematerializing the loads inside the loop past the "memory"-clobber
// barriers — R3/R4's 128-reg / L2-reload trap). k in [192,256) from 128 KB
// LDS Wl. waves_per_eu(2,2) -> 256-VGPR budget (live set ~245).
// Barrier: s_waitcnt vmcnt(3) lgkmcnt(0); s_barrier.
//   steady-state per-wave VM queue: {pref(t+1), stA(t-1), stB(t-1)} old +
//   {pref(t+2), stA(t), stB(t)} new; vmcnt(3) drains the old 3 -> x(t+1)
//   visible next step, newest prefetch + stores stay in flight.
// ---------------------------------------------------------------------------
__global__ __attribute__((amdgpu_flat_work_group_size(512,512), amdgpu_waves_per_eu(2,2)))
void lstm_rec(
    const f16* __restrict__ Wh_t, const f16* __restrict__ Wfrag,
    const f16* __restrict__ X, float* __restrict__ out)
{
  __shared__ f16 Wl[65536];        // 128 KB: [2 kfi][64 tile][64 lane][8]
  __shared__ f16 hbuf[2][256];
  __shared__ f16 xl[3][1024];      // rotating x buffers

  int b   = blockIdx.x;
  int tid = threadIdx.x;
  int w = tid >> 6, l = tid & 63, lr = l & 15, lg = l >> 4;

  // ---- prologue ----
  gload_lds4(X + (size_t)b*NC + tid*2,           &xl[0][w*128]);
  gload_lds4(X + (size_t)(BATCH + b)*NC + tid*2, &xl[1][w*128]);

  {
    const f16x8* srcp = (const f16x8*)Wfrag;
    f16x8* dstp = (f16x8*)Wl;
    #pragma unroll
    for (int i = 0; i < 16; ++i) dstp[tid + i*512] = srcp[tid + i*512];
  }
  // WB: k<192 B-fragments, col mapped per new wave->unit assignment
  f16x8 WB[8][6];
  #pragma unroll
  for (int nt = 0; nt < 8; ++nt) {
    int col = (nt>>1)*256 + w*32 + (nt&1)*16 + lr;
    const f16* basep = Wh_t + (size_t)col*256 + lg*8;
    #pragma unroll
    for (int kf = 0; kf < 6; ++kf) WB[nt][kf] = *(const f16x8*)(basep + kf*32);
  }
  // launder: opaque register values — cannot be rematerialized from memory
  #pragma unroll
  for (int nt = 0; nt < 8; ++nt)
    #pragma unroll
    for (int kf = 0; kf < 6; ++kf)
      asm volatile("" : "+v"(WB[nt][kf]));

  ((f16*)hbuf)[tid] = (f16)0.f;    // h0 = 0 (both buffers)
  float cA = 0.f, cB = 0.f;

  asm volatile("s_waitcnt vmcnt(0) lgkmcnt(0)" ::: "memory");
  __builtin_amdgcn_s_barrier();

  int xc = 0;   // buffer holding x_t
  for (int t = 0; t < SEQ; ++t) {
    int cur = t & 1;
    // A: prefetch x(t+2) into buffer that held x(t-1)
    if (t + 2 < SEQ) {
      int xn2 = (xc == 0) ? 2 : xc - 1;
      gload_lds4(X + ((size_t)(t+2)*BATCH + b)*NC + tid*2, &xl[xn2][w*128]);
    }
    // B: cf init from x_t
    const f16* xp = xl[xc];
    f32x4 cf[8];
    #pragma unroll
    for (int nt = 0; nt < 8; ++nt) {
      float xv = (float)xp[(nt>>1)*256 + w*32 + (nt&1)*16 + lr];
      cf[nt] = (f32x4){xv, xv, xv, xv};
    }
    // C: k < 192, B-operands from laundered registers
    #pragma unroll
    for (int kf = 0; kf < 6; ++kf) {
      f16x8 ha = *(const f16x8*)(&hbuf[cur][kf*32 + lg*8]);
      #pragma unroll
      for (int nt = 0; nt < 8; ++nt)
        cf[nt] = __builtin_amdgcn_mfma_f32_16x16x32_f16(ha, WB[nt][kf], cf[nt], 0, 0, 0);
    }
    // D: k in [192,256), B-operands streamed from LDS (conflict-free)
    #pragma unroll
    for (int kfi = 0; kfi < 2; ++kfi) {
      f16x8 ha = *(const f16x8*)(&hbuf[cur][(6+kfi)*32 + lg*8]);
      #pragma unroll
      for (int nt = 0; nt < 8; ++nt) {
        int tau = (nt>>1)*16 + w*2 + (nt&1);
        f16x8 wb = *(const f16x8*)(&Wl[(size_t)((kfi*64 + tau)*64 + l)*8]);
        cf[nt] = __builtin_amdgcn_mfma_f32_16x16x32_f16(ha, wb, cf[nt], 0, 0, 0);
      }
    }
    // E: lane-local activations + c/h update + h store (lanes 0..15 per wave)
    if (l < 16) {
      float iA = sigm_f(cf[0][0]), iB = sigm_f(cf[1][0]);
      float fA = sigm_f(cf[2][0]), fB = sigm_f(cf[3][0]);
      float gA = tanh_f(cf[4][0]), gB = tanh_f(cf[5][0]);
      float oA = sigm_f(cf[6][0]), oB = sigm_f(cf[7][0]);
      cA = fA*cA + iA*gA;
      cB = fB*cB + iB*gB;
      float hA = oA*tanh_f(cA);
      float hB = oB*tanh_f(cB);
      int uA = w*32 + lr, uB = uA + 16;
      hbuf[cur^1][uA] = (f16)hA;
      hbuf[cur^1][uB] = (f16)hB;
      float* op = out + ((size_t)t*BATCH + b)*HID;
      op[uA] = hA;
      op[uB] = hB;
    }
    // W: single barrier, counted waits
    asm volatile("s_waitcnt vmcnt(3) lgkmcnt(0)" ::: "memory");
    __builtin_amdgcn_s_barrier();

    xc = (xc == 2) ? 0 : xc + 1;
  }
}

// ---------------------------------------------------------------------------
extern "C" void kernel_launch(void* const* d_in, const int* in_sizes, int n_in,
                              void* d_out, int out_size, void* d_ws, size_t ws_size,
                              hipStream_t stream) {
  const float* emb = (const float*)d_in[0];
  const float* Wix = (const float*)d_in[1];
  const float* Wih = (const float*)d_in[2];
  const float* bi  = (const float*)d_in[3];
  const float* Wfx = (const float*)d_in[4];
  const float* Wfh = (const float*)d_in[5];
  const float* bf  = (const float*)d_in[6];
  const float* Wgx = (const float*)d_in[7];
  const float* Wgh = (const float*)d_in[8];
  const float* bg  = (const float*)d_in[9];
  const float* Wox = (const float*)d_in[10];
  const float* Woh = (const float*)d_in[11];
  const float* bo  = (const float*)d_in[12];

  char* ws = (char*)d_ws;
  f16* Wx_t  = (f16*)(ws);
  f16* Wh_t  = (f16*)(ws + 524288);
  f16* Wfrag = (f16*)(ws + 1048576);
  f16* Xp    = (f16*)(ws + 1179648);

  prep_w  <<<288,   256, 0, stream>>>(Wix, Wih, Wfx, Wfh, Wgx, Wgh, Wox, Woh,
                                      Wx_t, Wh_t, Wfrag);
  gemm_x  <<<32768, 256, 0, stream>>>(emb, Wx_t, bi, bf, bg, bo, Xp);
  lstm_rec<<<64,    512, 0, stream>>>(Wh_t, Wfrag, Xp, (float*)d_out);
}